// Round 3
// baseline (731.020 us; speedup 1.0000x reference)
//
#include <hip/hip_runtime.h>
#include <hip/hip_bf16.h>
#include <cstdint>

#define HID 256
#define NGRAPH 16
#define NEG_SLOPE 0.01f

typedef __bf16 bf16x8 __attribute__((ext_vector_type(8)));
typedef float f32x4 __attribute__((ext_vector_type(4)));

__device__ __forceinline__ float leaky(float x) { return x >= 0.f ? x : NEG_SLOPE * x; }

__device__ __forceinline__ ushort f2b(float f) {
  uint u = __float_as_uint(f);
  uint r = (u + 0x7fffu + ((u >> 16) & 1u)) >> 16;
  return (ushort)r;
}
__device__ __forceinline__ float b2f(ushort b) { return __uint_as_float((uint)b << 16); }

// ---------------- CSR build ----------------
__global__ __launch_bounds__(256) void k_zero_i32(int* p, int n) {
  int i = blockIdx.x * blockDim.x + threadIdx.x;
  if (i < n) p[i] = 0;
}

__global__ __launch_bounds__(256) void k_hist(const int* __restrict__ key, int* __restrict__ cnt, int ne) {
  int e = blockIdx.x * blockDim.x + threadIdx.x;
  if (e < ne) atomicAdd(&cnt[key[e]], 1);
}

__global__ __launch_bounds__(1024) void k_scan(const int* __restrict__ cnt, int* __restrict__ rowptr,
                                               int* __restrict__ cursor, int n) {
  __shared__ int sd[1024];
  int tid = threadIdx.x;
  int CH = n / 1024 + 1;
  int base = tid * CH;
  int s = 0;
  for (int i = 0; i < CH; ++i) { int idx = base + i; if (idx < n) s += cnt[idx]; }
  sd[tid] = s;
  __syncthreads();
  for (int off = 1; off < 1024; off <<= 1) {
    int v = (tid >= off) ? sd[tid - off] : 0;
    __syncthreads();
    sd[tid] += v;
    __syncthreads();
  }
  int run = (tid == 0) ? 0 : sd[tid - 1];
  for (int i = 0; i < CH; ++i) {
    int idx = base + i;
    if (idx <= n) {
      rowptr[idx] = run;
      if (idx < n) { cursor[idx] = run; run += cnt[idx]; }
    }
  }
}

// batch sorted -> per-graph bounds via binary search
__global__ __launch_bounds__(64) void k_gbounds(const int* __restrict__ batch, int n,
                                                int* __restrict__ gstart, int* __restrict__ gcnt) {
  int t = threadIdx.x;
  if (t <= NGRAPH) {
    int lo = 0, hi = n;
    while (lo < hi) { int mid = (lo + hi) >> 1; if (batch[mid] < t) lo = mid + 1; else hi = mid; }
    gstart[t] = lo;
  }
  __syncthreads();
  if (t < NGRAPH) gcnt[t] = gstart[t + 1] - gstart[t];
}

__global__ __launch_bounds__(256) void k_scatter(const int* __restrict__ src, const int* __restrict__ dst,
                                                 int* __restrict__ cursor, int* __restrict__ col, int ne) {
  int e = blockIdx.x * blockDim.x + threadIdx.x;
  if (e < ne) {
    int d = dst[e];
    int pos = atomicAdd(&cursor[d], 1);
    col[pos] = src[e];
  }
}

// ---------------- conversions ----------------
__global__ __launch_bounds__(256) void k_f2b(const float* __restrict__ src, ushort* __restrict__ dst, int nElem) {
  int i = (blockIdx.x * 256 + threadIdx.x) * 4;
  if (i + 3 < nElem) {
    float4 v = *(const float4*)&src[i];
    ushort4 o;
    o.x = f2b(v.x); o.y = f2b(v.y); o.z = f2b(v.z); o.w = f2b(v.w);
    *(ushort4*)&dst[i] = o;
  } else {
    for (int j = i; j < nElem; ++j) dst[j] = f2b(src[j]);
  }
}

// transpose-convert: dst[n][k] = bf16(src[k][n]); src is [K][256]
__global__ __launch_bounds__(256) void k_wconv(const float* __restrict__ src, ushort* __restrict__ dst, int K) {
  __shared__ float t[32][33];
  int k0 = blockIdx.x * 32;
  int n0 = blockIdx.y * 32;
  int tx = threadIdx.x & 31;
  int ty = threadIdx.x >> 5;
#pragma unroll
  for (int r = 0; r < 4; ++r) t[ty + 8 * r][tx] = src[(size_t)(k0 + ty + 8 * r) * 256 + n0 + tx];
  __syncthreads();
#pragma unroll
  for (int r = 0; r < 4; ++r) dst[(size_t)(n0 + ty + 8 * r) * K + k0 + tx] = f2b(t[tx][ty + 8 * r]);
}

// ---------------- aggregation ----------------
__global__ __launch_bounds__(256) void k_aggregate(const ushort* __restrict__ h, const int* __restrict__ rowptr,
                                                   const int* __restrict__ col, ushort* __restrict__ S,
                                                   ushort* __restrict__ hd, float* __restrict__ degf, int n) {
  int node = blockIdx.x * 4 + (threadIdx.x >> 6);
  if (node >= n) return;
  int lane = threadIdx.x & 63;
  const ushort4* h4 = (const ushort4*)h;
  size_t base = (size_t)node * 64 + lane;
  ushort4 self = h4[base];
  float a0 = b2f(self.x), a1 = b2f(self.y), a2 = b2f(self.z), a3 = b2f(self.w);
  float s0 = a0, s1 = a1, s2 = a2, s3 = a3;
  int beg = rowptr[node], end = rowptr[node + 1];
  for (int p = beg; p < end; ++p) {
    int j = col[p];
    ushort4 v = h4[(size_t)j * 64 + lane];
    s0 += b2f(v.x); s1 += b2f(v.y); s2 += b2f(v.z); s3 += b2f(v.w);
  }
  float deg = (float)(end - beg + 1);
  ushort4 so; so.x = f2b(s0); so.y = f2b(s1); so.z = f2b(s2); so.w = f2b(s3);
  ((ushort4*)S)[base] = so;
  ushort4 ho; ho.x = f2b(deg * a0); ho.y = f2b(deg * a1); ho.z = f2b(deg * a2); ho.w = f2b(deg * a3);
  ((ushort4*)hd)[base] = ho;
  if (lane == 0) degf[node] = deg;
}

// ---------------- bf16 MFMA GEMM: C = act( A0@W0t^T (+ A1@W1t^T) + rs.*bias ), N=256 fixed ----------------
// tile 128x128, 4 waves (2x2), wave tile 64x64, BK=32, double-buffered LDS, reg-staged, XOR k-slot swizzle.
__global__ __launch_bounds__(256) void k_gemm_bf16(
    const ushort* __restrict__ A0, const ushort* __restrict__ W0t, int ldw0,
    const ushort* __restrict__ A1, const ushort* __restrict__ W1t, int ldw1,
    const float* __restrict__ bias, const float* __restrict__ rowscale,
    ushort* __restrict__ C, int M, int K, int act)
{
  __shared__ __align__(16) ushort lds[2][2 * 128 * 32];  // [buf][A(4096) | B(4096)]
  const int tid = threadIdx.x;
  const int lane = tid & 63;
  const int wid = tid >> 6;
  const int wm = wid >> 1;   // 0..1 : rows [wm*64, +64)
  const int wn = wid & 1;    // 0..1 : cols [wn*64, +64)
  const int rl = lane & 15;
  const int kg = lane >> 4;  // k-group 0..3 (8 contig bf16)
  const int m0 = blockIdx.x * 128;
  const int n0 = blockIdx.y * 128;
  const int KS = K >> 5;
  const int NT = (A1 ? 2 : 1) * KS;

  f32x4 acc[4][4];
#pragma unroll
  for (int i = 0; i < 4; ++i)
#pragma unroll
    for (int j = 0; j < 4; ++j) acc[i][j] = (f32x4)(0.f);

  // slot s (0..511) -> row=s>>2, sl=s&3; LDS (row,sl) holds global k-group (sl ^ ((row>>1)&3))
  const int r0 = tid >> 2, r1 = (tid + 256) >> 2;
  const int sl = tid & 3;
  const int kg0 = sl ^ ((r0 >> 1) & 3);
  const int kg1 = sl ^ ((r1 >> 1) & 3);
  int ga0 = m0 + r0; if (ga0 > M - 1) ga0 = M - 1;
  int ga1 = m0 + r1; if (ga1 > M - 1) ga1 = M - 1;
  const int gb0 = n0 + r0;
  const int gb1 = n0 + r1;

  bf16x8 ra0, ra1, rb0, rb1;

#define LOAD_TILE(t)                                                                   \
  {                                                                                    \
    int p_ = (t) / KS;                                                                 \
    int k0_ = ((t) - p_ * KS) << 5;                                                    \
    const ushort* Ap_ = p_ ? A1 : A0;                                                  \
    const ushort* Wp_ = p_ ? W1t : W0t;                                                \
    int ldw_ = p_ ? ldw1 : ldw0;                                                       \
    ra0 = *(const bf16x8*)&Ap_[(size_t)ga0 * K + k0_ + kg0 * 8];                       \
    ra1 = *(const bf16x8*)&Ap_[(size_t)ga1 * K + k0_ + kg1 * 8];                       \
    rb0 = *(const bf16x8*)&Wp_[(size_t)gb0 * ldw_ + k0_ + kg0 * 8];                    \
    rb1 = *(const bf16x8*)&Wp_[(size_t)gb1 * ldw_ + k0_ + kg1 * 8];                    \
  }

#define STORE_TILE(b)                                                                  \
  {                                                                                    \
    ushort* dA_ = &lds[b][0];                                                          \
    ushort* dB_ = &lds[b][4096];                                                       \
    *(bf16x8*)&dA_[(size_t)tid * 8] = ra0;                                             \
    *(bf16x8*)&dA_[(size_t)(tid + 256) * 8] = ra1;                                     \
    *(bf16x8*)&dB_[(size_t)tid * 8] = rb0;                                             \
    *(bf16x8*)&dB_[(size_t)(tid + 256) * 8] = rb1;                                     \
  }

  LOAD_TILE(0);
  STORE_TILE(0);

  for (int t = 0; t < NT; ++t) {
    if (t + 1 < NT) LOAD_TILE(t + 1);
    __syncthreads();
    const ushort* bA = &lds[t & 1][0];
    const ushort* bB = &lds[t & 1][4096];
    bf16x8 af[4], bfr[4];
#pragma unroll
    for (int fm = 0; fm < 4; ++fm) {
      int r = wm * 64 + fm * 16 + rl;
      int s = kg ^ ((r >> 1) & 3);
      af[fm] = *(const bf16x8*)&bA[r * 32 + s * 8];
    }
#pragma unroll
    for (int fn = 0; fn < 4; ++fn) {
      int rn = wn * 64 + fn * 16 + rl;
      int s = kg ^ ((rn >> 1) & 3);
      bfr[fn] = *(const bf16x8*)&bB[rn * 32 + s * 8];
    }
#pragma unroll
    for (int fm = 0; fm < 4; ++fm)
#pragma unroll
      for (int fn = 0; fn < 4; ++fn)
        acc[fm][fn] = __builtin_amdgcn_mfma_f32_16x16x32_bf16(af[fm], bfr[fn], acc[fm][fn], 0, 0, 0);
    if (t + 1 < NT) STORE_TILE((t + 1) & 1);
  }

  // epilogue: C/D layout col=lane&15, row=(lane>>4)*4+reg  [m89/m91]
  const int colb = n0 + wn * 64;
#pragma unroll
  for (int fm = 0; fm < 4; ++fm) {
    int row0 = m0 + wm * 64 + fm * 16 + kg * 4;
#pragma unroll
    for (int fn = 0; fn < 4; ++fn) {
      int c = colb + fn * 16 + rl;
      float bv = bias[c];
#pragma unroll
      for (int rg = 0; rg < 4; ++rg) {
        int row = row0 + rg;
        if (row < M) {
          float rs = rowscale ? rowscale[row] : 1.0f;
          float v = acc[fm][fn][rg] + rs * bv;
          if (act) v = leaky(v);
          C[(size_t)row * 256 + c] = f2b(v);
        }
      }
    }
  }
#undef LOAD_TILE
#undef STORE_TILE
}

// ---------------- fused decoder: one block per graph ----------------
// pooled[16][768] -> L1 768->256 leaky -> L2,L3 256->256 leaky -> L4 256->32
__global__ __launch_bounds__(256) void k_decoder(
    const float* __restrict__ pooled,
    const float* __restrict__ Win, const float* __restrict__ bin,
    const float* __restrict__ Wh, const float* __restrict__ bh,
    const float* __restrict__ Wout, const float* __restrict__ bout,
    float* __restrict__ out)
{
  __shared__ float buf0[768];
  __shared__ float buf1[256];
  __shared__ float red[8][32];
  int g = blockIdx.x, t = threadIdx.x;
  buf0[t] = pooled[g * 768 + t];
  buf0[t + 256] = pooled[g * 768 + 256 + t];
  buf0[t + 512] = pooled[g * 768 + 512 + t];
  __syncthreads();
  // L1: 768 -> 256
  float acc = bin[t];
#pragma unroll 8
  for (int k = 0; k < 768; ++k) acc += buf0[k] * Win[(size_t)k * 256 + t];
  buf1[t] = leaky(acc);
  __syncthreads();
  // L2: 256 -> 256
  acc = bh[t];
#pragma unroll 8
  for (int k = 0; k < 256; ++k) acc += buf1[k] * Wh[(size_t)k * 256 + t];
  buf0[t] = leaky(acc);
  __syncthreads();
  // L3: 256 -> 256
  acc = bh[256 + t];
#pragma unroll 8
  for (int k = 0; k < 256; ++k) acc += buf0[k] * Wh[65536 + (size_t)k * 256 + t];
  buf1[t] = leaky(acc);
  __syncthreads();
  // L4: 256 -> 32, 8-way K-split
  int colo = t & 31, seg = t >> 5;
  float a = 0.f;
#pragma unroll
  for (int k = seg * 32; k < seg * 32 + 32; ++k) a += buf1[k] * Wout[(size_t)k * 32 + colo];
  red[seg][colo] = a;
  __syncthreads();
  if (t < 32) {
    float s = bout[t];
#pragma unroll
    for (int i = 0; i < 8; ++i) s += red[i][t];
    out[g * 32 + t] = s;
  }
}

// ---------------- pooling ----------------
__global__ __launch_bounds__(256) void k_pool1(const ushort* __restrict__ h, const int* __restrict__ gstart,
                                               const int* __restrict__ gcnt, float* __restrict__ psum,
                                               float* __restrict__ pmax) {
  int g = blockIdx.x >> 4;
  int cch = blockIdx.x & 15;
  int t = threadIdx.x;
  int len = gcnt[g];
  int s0 = gstart[g];
  int chunk = (len + 15) >> 4;
  int i0 = s0 + cch * chunk;
  int i1 = min(i0 + chunk, s0 + len);
  float s = 0.f;
  float m = -3.402823466e+38f;
  for (int i = i0; i < i1; ++i) {
    float v = b2f(h[(size_t)i * HID + t]);
    s += v;
    m = fmaxf(m, v);
  }
  psum[(size_t)blockIdx.x * HID + t] = s;
  pmax[(size_t)blockIdx.x * HID + t] = m;
}

__global__ __launch_bounds__(256) void k_pool2(const float* __restrict__ psum, const float* __restrict__ pmax,
                                               const int* __restrict__ gcnt, float* __restrict__ pooled) {
  int g = blockIdx.x;
  int t = threadIdx.x;
  float s = 0.f, m = -3.402823466e+38f;
  for (int cch = 0; cch < 16; ++cch) {
    s += psum[(size_t)(g * 16 + cch) * HID + t];
    m = fmaxf(m, pmax[(size_t)(g * 16 + cch) * HID + t]);
  }
  float cf = (float)gcnt[g];
  pooled[g * 3 * HID + t] = s / fmaxf(cf, 1.f);
  pooled[g * 3 * HID + HID + t] = m;
  pooled[g * 3 * HID + 2 * HID + t] = s;
}

// ---------------- launch ----------------
extern "C" void kernel_launch(void* const* d_in, const int* in_sizes, int n_in,
                              void* d_out, int out_size, void* d_ws, size_t ws_size,
                              hipStream_t stream) {
  const float* x        = (const float*)d_in[0];
  const int*   ei       = (const int*)d_in[1];
  const int*   batch    = (const int*)d_in[2];
  const float* enc_Win  = (const float*)d_in[3];
  const float* enc_bin  = (const float*)d_in[4];
  const float* enc_Wh   = (const float*)d_in[5];
  const float* enc_bh   = (const float*)d_in[6];
  const float* enc_Wout = (const float*)d_in[7];
  const float* enc_bout = (const float*)d_in[8];
  const float* edge_W   = (const float*)d_in[9];
  const float* edge_b   = (const float*)d_in[10];
  const float* proc_Win = (const float*)d_in[11];
  const float* proc_bin = (const float*)d_in[12];
  const float* proc_Wh  = (const float*)d_in[13];
  const float* proc_bh  = (const float*)d_in[14];
  const float* proc_Wout= (const float*)d_in[15];
  const float* proc_bout= (const float*)d_in[16];
  const float* dec_Win  = (const float*)d_in[17];
  const float* dec_bin  = (const float*)d_in[18];
  const float* dec_Wh   = (const float*)d_in[19];
  const float* dec_bh   = (const float*)d_in[20];
  const float* dec_Wout = (const float*)d_in[21];
  const float* dec_bout = (const float*)d_in[22];

  const int n  = in_sizes[0] / 128;  // 20000
  const int ne = in_sizes[1] / 2;    // 160000
  const int H = HID;

  char* p = (char*)d_ws;
  auto alloc = [&](size_t bytes) -> char* {
    char* r = p;
    p += (bytes + 255) & ~(size_t)255;
    return r;
  };
  ushort* hb0   = (ushort*)alloc((size_t)n * H * 2);
  ushort* hb1   = (ushort*)alloc((size_t)n * H * 2);
  ushort* Sb    = (ushort*)alloc((size_t)n * H * 2);
  ushort* hdb   = (ushort*)alloc((size_t)n * H * 2);
  ushort* xb    = (ushort*)alloc((size_t)n * 128 * 2);
  ushort* w_enc_in  = (ushort*)alloc((size_t)256 * 128 * 2);
  ushort* w_enc_h0  = (ushort*)alloc((size_t)256 * 256 * 2);
  ushort* w_enc_h1  = (ushort*)alloc((size_t)256 * 256 * 2);
  ushort* w_enc_out = (ushort*)alloc((size_t)256 * 256 * 2);
  ushort* w_proc_in  = (ushort*)alloc((size_t)256 * 256 * 2);
  ushort* w_proc_h0  = (ushort*)alloc((size_t)256 * 256 * 2);
  ushort* w_proc_h1  = (ushort*)alloc((size_t)256 * 256 * 2);
  ushort* w_proc_out = (ushort*)alloc((size_t)256 * 256 * 2);
  ushort* w_edge     = (ushort*)alloc((size_t)256 * 512 * 2);
  float* degf   = (float*)alloc((size_t)n * 4);
  float* pooled = (float*)alloc((size_t)NGRAPH * 3 * H * 4);
  float* psum   = (float*)alloc((size_t)256 * H * 4);
  float* pmax   = (float*)alloc((size_t)256 * H * 4);
  int* cnt    = (int*)alloc((size_t)n * 4);
  int* rowptr = (int*)alloc((size_t)(n + 1) * 4);
  int* cursor = (int*)alloc((size_t)n * 4);
  int* gstart = (int*)alloc((size_t)(NGRAPH + 1) * 4);
  int* gcnt   = (int*)alloc((size_t)NGRAPH * 4);
  int* colv   = (int*)alloc((size_t)ne * 4);

  const int* srcI = ei;
  const int* dstI = ei + ne;

  dim3 blk(256);

  // weight conversions (transpose to [N=256][K] bf16)
  k_wconv<<<dim3(128 / 32, 8), blk, 0, stream>>>(enc_Win, w_enc_in, 128);
  k_wconv<<<dim3(256 / 32, 8), blk, 0, stream>>>(enc_Wh, w_enc_h0, 256);
  k_wconv<<<dim3(256 / 32, 8), blk, 0, stream>>>(enc_Wh + 256 * 256, w_enc_h1, 256);
  k_wconv<<<dim3(256 / 32, 8), blk, 0, stream>>>(enc_Wout, w_enc_out, 256);
  k_wconv<<<dim3(256 / 32, 8), blk, 0, stream>>>(proc_Win, w_proc_in, 256);
  k_wconv<<<dim3(256 / 32, 8), blk, 0, stream>>>(proc_Wh, w_proc_h0, 256);
  k_wconv<<<dim3(256 / 32, 8), blk, 0, stream>>>(proc_Wh + 256 * 256, w_proc_h1, 256);
  k_wconv<<<dim3(256 / 32, 8), blk, 0, stream>>>(proc_Wout, w_proc_out, 256);
  k_wconv<<<dim3(512 / 32, 8), blk, 0, stream>>>(edge_W, w_edge, 512);
  k_f2b<<<dim3((n * 128 / 4 + 255) / 256), blk, 0, stream>>>(x, xb, n * 128);

  // CSR by destination + per-graph bounds
  k_zero_i32<<<dim3((n + 255) / 256), blk, 0, stream>>>(cnt, n);
  k_hist<<<dim3((ne + 255) / 256), blk, 0, stream>>>(dstI, cnt, ne);
  k_scan<<<1, 1024, 0, stream>>>(cnt, rowptr, cursor, n);
  k_gbounds<<<1, 64, 0, stream>>>(batch, n, gstart, gcnt);
  k_scatter<<<dim3((ne + 255) / 256), blk, 0, stream>>>(srcI, dstI, cursor, colv, ne);

  dim3 gg((n + 127) / 128, 2);  // 128x128 tiles

  // encoder
  k_gemm_bf16<<<gg, blk, 0, stream>>>(xb,  w_enc_in, 128, nullptr, nullptr, 0, enc_bin,      nullptr, hb0, n, 128, 1);
  k_gemm_bf16<<<gg, blk, 0, stream>>>(hb0, w_enc_h0, 256, nullptr, nullptr, 0, enc_bh,       nullptr, hb1, n, 256, 1);
  k_gemm_bf16<<<gg, blk, 0, stream>>>(hb1, w_enc_h1, 256, nullptr, nullptr, 0, enc_bh + 256, nullptr, hb0, n, 256, 1);
  k_gemm_bf16<<<gg, blk, 0, stream>>>(hb0, w_enc_out, 256, nullptr, nullptr, 0, enc_bout,    nullptr, hb1, n, 256, 0);

  // 4 message-passing rounds; h in hb1 at loop head
  for (int r = 0; r < 4; ++r) {
    k_aggregate<<<dim3((n + 3) / 4), blk, 0, stream>>>(hb1, rowptr, colv, Sb, hdb, degf, n);
    k_gemm_bf16<<<gg, blk, 0, stream>>>(hdb, w_edge, 512, Sb, w_edge + 256, 512, edge_b, degf, hb0, n, 256, 0);
    k_gemm_bf16<<<gg, blk, 0, stream>>>(hb0, w_proc_in, 256, nullptr, nullptr, 0, proc_bin,       nullptr, Sb,  n, 256, 1);
    k_gemm_bf16<<<gg, blk, 0, stream>>>(Sb,  w_proc_h0, 256, nullptr, nullptr, 0, proc_bh,        nullptr, hb0, n, 256, 1);
    k_gemm_bf16<<<gg, blk, 0, stream>>>(hb0, w_proc_h1, 256, nullptr, nullptr, 0, proc_bh + 256,  nullptr, Sb,  n, 256, 1);
    k_gemm_bf16<<<gg, blk, 0, stream>>>(Sb,  w_proc_out, 256, nullptr, nullptr, 0, proc_bout,     nullptr, hb1, n, 256, 0);
  }

  // pooling
  k_pool1<<<dim3(NGRAPH * 16), blk, 0, stream>>>(hb1, gstart, gcnt, psum, pmax);
  k_pool2<<<dim3(NGRAPH), blk, 0, stream>>>(psum, pmax, gcnt, pooled);

  // fused decoder
  k_decoder<<<dim3(NGRAPH), blk, 0, stream>>>(pooled, dec_Win, dec_bin, dec_Wh, dec_bh,
                                              dec_Wout, dec_bout, (float*)d_out);
}

// Round 4
// 560.501 us; speedup vs baseline: 1.3042x; 1.3042x over previous
//
#include <hip/hip_runtime.h>
#include <hip/hip_bf16.h>
#include <cstdint>

#define HID 256
#define NGRAPH 16
#define NEG_SLOPE 0.01f

typedef __bf16 bf16x8 __attribute__((ext_vector_type(8)));
typedef float f32x4 __attribute__((ext_vector_type(4)));

__device__ __forceinline__ float leaky(float x) { return x >= 0.f ? x : NEG_SLOPE * x; }

__device__ __forceinline__ ushort f2b(float f) {
  uint u = __float_as_uint(f);
  uint r = (u + 0x7fffu + ((u >> 16) & 1u)) >> 16;
  return (ushort)r;
}
__device__ __forceinline__ float b2f(ushort b) { return __uint_as_float((uint)b << 16); }

// ---------------- CSR build ----------------
__global__ __launch_bounds__(256) void k_zero_i32(int* p, int n) {
  int i = blockIdx.x * blockDim.x + threadIdx.x;
  if (i < n) p[i] = 0;
}

__global__ __launch_bounds__(256) void k_hist(const int* __restrict__ key, int* __restrict__ cnt, int ne) {
  int e = blockIdx.x * blockDim.x + threadIdx.x;
  if (e < ne) atomicAdd(&cnt[key[e]], 1);
}

__global__ __launch_bounds__(1024) void k_scan(const int* __restrict__ cnt, int* __restrict__ rowptr,
                                               int* __restrict__ cursor, int n) {
  __shared__ int sd[1024];
  int tid = threadIdx.x;
  int CH = n / 1024 + 1;
  int base = tid * CH;
  int s = 0;
  for (int i = 0; i < CH; ++i) { int idx = base + i; if (idx < n) s += cnt[idx]; }
  sd[tid] = s;
  __syncthreads();
  for (int off = 1; off < 1024; off <<= 1) {
    int v = (tid >= off) ? sd[tid - off] : 0;
    __syncthreads();
    sd[tid] += v;
    __syncthreads();
  }
  int run = (tid == 0) ? 0 : sd[tid - 1];
  for (int i = 0; i < CH; ++i) {
    int idx = base + i;
    if (idx <= n) {
      rowptr[idx] = run;
      if (idx < n) { cursor[idx] = run; run += cnt[idx]; }
    }
  }
}

// batch sorted -> per-graph bounds via binary search
__global__ __launch_bounds__(64) void k_gbounds(const int* __restrict__ batch, int n,
                                                int* __restrict__ gstart, int* __restrict__ gcnt) {
  int t = threadIdx.x;
  if (t <= NGRAPH) {
    int lo = 0, hi = n;
    while (lo < hi) { int mid = (lo + hi) >> 1; if (batch[mid] < t) lo = mid + 1; else hi = mid; }
    gstart[t] = lo;
  }
  __syncthreads();
  if (t < NGRAPH) gcnt[t] = gstart[t + 1] - gstart[t];
}

__global__ __launch_bounds__(256) void k_scatter(const int* __restrict__ src, const int* __restrict__ dst,
                                                 int* __restrict__ cursor, int* __restrict__ col, int ne) {
  int e = blockIdx.x * blockDim.x + threadIdx.x;
  if (e < ne) {
    int d = dst[e];
    int pos = atomicAdd(&cursor[d], 1);
    col[pos] = src[e];
  }
}

// ---------------- conversions ----------------
__global__ __launch_bounds__(256) void k_f2b(const float* __restrict__ src, ushort* __restrict__ dst, int nElem) {
  int i = (blockIdx.x * 256 + threadIdx.x) * 4;
  if (i + 3 < nElem) {
    float4 v = *(const float4*)&src[i];
    ushort4 o;
    o.x = f2b(v.x); o.y = f2b(v.y); o.z = f2b(v.z); o.w = f2b(v.w);
    *(ushort4*)&dst[i] = o;
  } else {
    for (int j = i; j < nElem; ++j) dst[j] = f2b(src[j]);
  }
}

// transpose-convert: dst[n][k] = bf16(src[k][n]); src is [K][256]
__global__ __launch_bounds__(256) void k_wconv(const float* __restrict__ src, ushort* __restrict__ dst, int K) {
  __shared__ float t[32][33];
  int k0 = blockIdx.x * 32;
  int n0 = blockIdx.y * 32;
  int tx = threadIdx.x & 31;
  int ty = threadIdx.x >> 5;
#pragma unroll
  for (int r = 0; r < 4; ++r) t[ty + 8 * r][tx] = src[(size_t)(k0 + ty + 8 * r) * 256 + n0 + tx];
  __syncthreads();
#pragma unroll
  for (int r = 0; r < 4; ++r) dst[(size_t)(n0 + ty + 8 * r) * K + k0 + tx] = f2b(t[tx][ty + 8 * r]);
}

// ---------------- aggregation ----------------
__global__ __launch_bounds__(256) void k_aggregate(const ushort* __restrict__ h, const int* __restrict__ rowptr,
                                                   const int* __restrict__ col, ushort* __restrict__ S,
                                                   ushort* __restrict__ hd, float* __restrict__ degf, int n) {
  int node = blockIdx.x * 4 + (threadIdx.x >> 6);
  if (node >= n) return;
  int lane = threadIdx.x & 63;
  const ushort4* h4 = (const ushort4*)h;
  size_t base = (size_t)node * 64 + lane;
  ushort4 self = h4[base];
  float a0 = b2f(self.x), a1 = b2f(self.y), a2 = b2f(self.z), a3 = b2f(self.w);
  float s0 = a0, s1 = a1, s2 = a2, s3 = a3;
  int beg = rowptr[node], end = rowptr[node + 1];
  for (int p = beg; p < end; ++p) {
    int j = col[p];
    ushort4 v = h4[(size_t)j * 64 + lane];
    s0 += b2f(v.x); s1 += b2f(v.y); s2 += b2f(v.z); s3 += b2f(v.w);
  }
  float deg = (float)(end - beg + 1);
  ushort4 so; so.x = f2b(s0); so.y = f2b(s1); so.z = f2b(s2); so.w = f2b(s3);
  ((ushort4*)S)[base] = so;
  ushort4 ho; ho.x = f2b(deg * a0); ho.y = f2b(deg * a1); ho.z = f2b(deg * a2); ho.w = f2b(deg * a3);
  ((ushort4*)hd)[base] = ho;
  if (lane == 0) degf[node] = deg;
}

// ---------------- bf16 MFMA GEMM: C = act( A0@W0t^T (+ A1@W1t^T) + rs.*bias ), N=256 fixed ----------------
// tile 128x64, 4 waves (2x2), wave tile 64x32, BK=32, double-buffered LDS, reg-staged, XOR k-slot swizzle.
// grid: 1-D flattened (MT*4 blocks), bijective XCD-chunked swizzle, n-fastest decode.
__global__ __launch_bounds__(256) void k_gemm_bf16(
    const ushort* __restrict__ A0, const ushort* __restrict__ W0t, int ldw0,
    const ushort* __restrict__ A1, const ushort* __restrict__ W1t, int ldw1,
    const float* __restrict__ bias, const float* __restrict__ rowscale,
    ushort* __restrict__ C, int M, int K, int act)
{
  __shared__ __align__(16) ushort lds[2][128 * 32 + 64 * 32];
  // bijective XCD-chunked remap (m204): consecutive wgids land on one XCD
  const int nwg = gridDim.x;
  const int q = nwg >> 3, r = nwg & 7;
  const int orig = blockIdx.x;
  const int xcd = orig & 7, base_i = orig >> 3;
  const int wgid = (xcd < r ? xcd * (q + 1) : r * (q + 1) + (xcd - r) * q) + base_i;
  const int mi = wgid >> 2;       // m-tile
  const int ni = wgid & 3;        // n-tile (4 share one A-panel -> same XCD)

  const int tid = threadIdx.x;
  const int lane = tid & 63;
  const int wid = tid >> 6;
  const int wm = wid >> 1;   // 0..1 : rows [wm*64, +64)
  const int wn = wid & 1;    // 0..1 : cols [wn*32, +32)
  const int rl = lane & 15;
  const int kg = lane >> 4;  // k-group 0..3 (8 contig bf16)
  const int m0 = mi * 128;
  const int n0 = ni * 64;
  const int KS = K >> 5;
  const int NT = (A1 ? 2 : 1) * KS;

  f32x4 acc[4][2];
#pragma unroll
  for (int i = 0; i < 4; ++i)
#pragma unroll
    for (int j = 0; j < 2; ++j) acc[i][j] = (f32x4)(0.f);

  // slot s -> row=s>>2, sl=s&3; LDS (row,sl) holds global k-group (sl ^ ((row>>1)&3))
  const int a_row0 = tid >> 2, a_sl0 = tid & 3;
  const int a_row1 = (tid + 256) >> 2;
  const int a_kg0 = a_sl0 ^ ((a_row0 >> 1) & 3);
  const int a_kg1 = a_sl0 ^ ((a_row1 >> 1) & 3);
  const int b_row = tid >> 2, b_sl = tid & 3;
  const int b_kg = b_sl ^ ((b_row >> 1) & 3);
  int ga0 = m0 + a_row0; if (ga0 > M - 1) ga0 = M - 1;
  int ga1 = m0 + a_row1; if (ga1 > M - 1) ga1 = M - 1;

  bf16x8 ra0, ra1, rb;

#define LOAD_TILE(t)                                                                   \
  {                                                                                    \
    int p_ = (t) / KS;                                                                 \
    int k0_ = ((t) - p_ * KS) << 5;                                                    \
    const ushort* Ap_ = p_ ? A1 : A0;                                                  \
    const ushort* Wp_ = p_ ? W1t : W0t;                                                \
    int ldw_ = p_ ? ldw1 : ldw0;                                                       \
    ra0 = *(const bf16x8*)&Ap_[(size_t)ga0 * K + k0_ + a_kg0 * 8];                     \
    ra1 = *(const bf16x8*)&Ap_[(size_t)ga1 * K + k0_ + a_kg1 * 8];                     \
    rb  = *(const bf16x8*)&Wp_[(size_t)(n0 + b_row) * ldw_ + k0_ + b_kg * 8];          \
  }

#define STORE_TILE(b)                                                                  \
  {                                                                                    \
    ushort* dA_ = &lds[b][0];                                                          \
    ushort* dB_ = &lds[b][128 * 32];                                                   \
    *(bf16x8*)&dA_[(size_t)tid * 8] = ra0;                                             \
    *(bf16x8*)&dA_[(size_t)(tid + 256) * 8] = ra1;                                     \
    *(bf16x8*)&dB_[(size_t)tid * 8] = rb;                                              \
  }

  LOAD_TILE(0);
  STORE_TILE(0);

  for (int t = 0; t < NT; ++t) {
    if (t + 1 < NT) LOAD_TILE(t + 1);
    __syncthreads();
    const ushort* bA = &lds[t & 1][0];
    const ushort* bB = &lds[t & 1][128 * 32];
    bf16x8 af[4], bfr[2];
#pragma unroll
    for (int fm = 0; fm < 4; ++fm) {
      int rr = wm * 64 + fm * 16 + rl;
      int s = kg ^ ((rr >> 1) & 3);
      af[fm] = *(const bf16x8*)&bA[rr * 32 + s * 8];
    }
#pragma unroll
    for (int fn = 0; fn < 2; ++fn) {
      int rn = wn * 32 + fn * 16 + rl;
      int s = kg ^ ((rn >> 1) & 3);
      bfr[fn] = *(const bf16x8*)&bB[rn * 32 + s * 8];
    }
#pragma unroll
    for (int fm = 0; fm < 4; ++fm)
#pragma unroll
      for (int fn = 0; fn < 2; ++fn)
        acc[fm][fn] = __builtin_amdgcn_mfma_f32_16x16x32_bf16(af[fm], bfr[fn], acc[fm][fn], 0, 0, 0);
    if (t + 1 < NT) STORE_TILE((t + 1) & 1);
  }

  // epilogue: C/D layout col=lane&15, row=(lane>>4)*4+reg  [m89/m91]
  const int colb = n0 + wn * 32;
#pragma unroll
  for (int fm = 0; fm < 4; ++fm) {
    int row0 = m0 + wm * 64 + fm * 16 + kg * 4;
#pragma unroll
    for (int fn = 0; fn < 2; ++fn) {
      int c = colb + fn * 16 + rl;
      float bv = bias[c];
#pragma unroll
      for (int rg = 0; rg < 4; ++rg) {
        int row = row0 + rg;
        if (row < M) {
          float rs = rowscale ? rowscale[row] : 1.0f;
          float v = acc[fm][fn][rg] + rs * bv;
          if (act) v = leaky(v);
          C[(size_t)row * 256 + c] = f2b(v);
        }
      }
    }
  }
#undef LOAD_TILE
#undef STORE_TILE
}

// ---------------- decoder layer: out[G][N] = act(A[G][K] @ W[K][N] + b) ----------------
// grid: (N/cols, G); 256 thr = cols x segs; activation row LDS-resident; LDS K-seg reduce.
__global__ __launch_bounds__(256) void k_dec_layer(
    const float* __restrict__ A, const float* __restrict__ W,
    const float* __restrict__ bias, float* __restrict__ out,
    int K, int N, int act)
{
  __shared__ float a[768];
  __shared__ float red[8][64];
  const int g = blockIdx.y;
  const int cols = (N >= 64) ? 64 : 32;
  const int segs = 256 / cols;
  const int t = threadIdx.x;
  const int col = t % cols, seg = t / cols;
  const int c = blockIdx.x * cols + col;
  for (int i = t; i < K; i += 256) a[i] = A[(size_t)g * K + i];
  __syncthreads();
  const int kper = K / segs;
  const int k0 = seg * kper;
  float p = 0.f;
#pragma unroll 8
  for (int k = k0; k < k0 + kper; ++k) p += a[k] * W[(size_t)k * N + c];
  red[seg][col] = p;
  __syncthreads();
  if (seg == 0) {
    float s = bias[c];
    for (int i = 0; i < segs; ++i) s += red[i][col];
    out[(size_t)g * N + c] = act ? leaky(s) : s;
  }
}

// ---------------- pooling ----------------
__global__ __launch_bounds__(256) void k_pool1(const ushort* __restrict__ h, const int* __restrict__ gstart,
                                               const int* __restrict__ gcnt, float* __restrict__ psum,
                                               float* __restrict__ pmax) {
  int g = blockIdx.x >> 4;
  int cch = blockIdx.x & 15;
  int t = threadIdx.x;
  int len = gcnt[g];
  int s0 = gstart[g];
  int chunk = (len + 15) >> 4;
  int i0 = s0 + cch * chunk;
  int i1 = min(i0 + chunk, s0 + len);
  float s = 0.f;
  float m = -3.402823466e+38f;
  for (int i = i0; i < i1; ++i) {
    float v = b2f(h[(size_t)i * HID + t]);
    s += v;
    m = fmaxf(m, v);
  }
  psum[(size_t)blockIdx.x * HID + t] = s;
  pmax[(size_t)blockIdx.x * HID + t] = m;
}

__global__ __launch_bounds__(256) void k_pool2(const float* __restrict__ psum, const float* __restrict__ pmax,
                                               const int* __restrict__ gcnt, float* __restrict__ pooled) {
  int g = blockIdx.x;
  int t = threadIdx.x;
  float s = 0.f, m = -3.402823466e+38f;
  for (int cch = 0; cch < 16; ++cch) {
    s += psum[(size_t)(g * 16 + cch) * HID + t];
    m = fmaxf(m, pmax[(size_t)(g * 16 + cch) * HID + t]);
  }
  float cf = (float)gcnt[g];
  pooled[g * 3 * HID + t] = s / fmaxf(cf, 1.f);
  pooled[g * 3 * HID + HID + t] = m;
  pooled[g * 3 * HID + 2 * HID + t] = s;
}

// ---------------- launch ----------------
extern "C" void kernel_launch(void* const* d_in, const int* in_sizes, int n_in,
                              void* d_out, int out_size, void* d_ws, size_t ws_size,
                              hipStream_t stream) {
  const float* x        = (const float*)d_in[0];
  const int*   ei       = (const int*)d_in[1];
  const int*   batch    = (const int*)d_in[2];
  const float* enc_Win  = (const float*)d_in[3];
  const float* enc_bin  = (const float*)d_in[4];
  const float* enc_Wh   = (const float*)d_in[5];
  const float* enc_bh   = (const float*)d_in[6];
  const float* enc_Wout = (const float*)d_in[7];
  const float* enc_bout = (const float*)d_in[8];
  const float* edge_W   = (const float*)d_in[9];
  const float* edge_b   = (const float*)d_in[10];
  const float* proc_Win = (const float*)d_in[11];
  const float* proc_bin = (const float*)d_in[12];
  const float* proc_Wh  = (const float*)d_in[13];
  const float* proc_bh  = (const float*)d_in[14];
  const float* proc_Wout= (const float*)d_in[15];
  const float* proc_bout= (const float*)d_in[16];
  const float* dec_Win  = (const float*)d_in[17];
  const float* dec_bin  = (const float*)d_in[18];
  const float* dec_Wh   = (const float*)d_in[19];
  const float* dec_bh   = (const float*)d_in[20];
  const float* dec_Wout = (const float*)d_in[21];
  const float* dec_bout = (const float*)d_in[22];

  const int n  = in_sizes[0] / 128;  // 20000
  const int ne = in_sizes[1] / 2;    // 160000
  const int H = HID;

  char* p = (char*)d_ws;
  auto alloc = [&](size_t bytes) -> char* {
    char* r = p;
    p += (bytes + 255) & ~(size_t)255;
    return r;
  };
  ushort* hb0   = (ushort*)alloc((size_t)n * H * 2);
  ushort* hb1   = (ushort*)alloc((size_t)n * H * 2);
  ushort* Sb    = (ushort*)alloc((size_t)n * H * 2);
  ushort* hdb   = (ushort*)alloc((size_t)n * H * 2);
  ushort* xb    = (ushort*)alloc((size_t)n * 128 * 2);
  ushort* w_enc_in  = (ushort*)alloc((size_t)256 * 128 * 2);
  ushort* w_enc_h0  = (ushort*)alloc((size_t)256 * 256 * 2);
  ushort* w_enc_h1  = (ushort*)alloc((size_t)256 * 256 * 2);
  ushort* w_enc_out = (ushort*)alloc((size_t)256 * 256 * 2);
  ushort* w_proc_in  = (ushort*)alloc((size_t)256 * 256 * 2);
  ushort* w_proc_h0  = (ushort*)alloc((size_t)256 * 256 * 2);
  ushort* w_proc_h1  = (ushort*)alloc((size_t)256 * 256 * 2);
  ushort* w_proc_out = (ushort*)alloc((size_t)256 * 256 * 2);
  ushort* w_edge     = (ushort*)alloc((size_t)256 * 512 * 2);
  float* degf   = (float*)alloc((size_t)n * 4);
  float* pooled = (float*)alloc((size_t)NGRAPH * 3 * H * 4);
  float* psum   = (float*)alloc((size_t)256 * H * 4);
  float* pmax   = (float*)alloc((size_t)256 * H * 4);
  float* db0    = (float*)alloc((size_t)NGRAPH * H * 4);
  float* db1    = (float*)alloc((size_t)NGRAPH * H * 4);
  int* cnt    = (int*)alloc((size_t)n * 4);
  int* rowptr = (int*)alloc((size_t)(n + 1) * 4);
  int* cursor = (int*)alloc((size_t)n * 4);
  int* gstart = (int*)alloc((size_t)(NGRAPH + 1) * 4);
  int* gcnt   = (int*)alloc((size_t)NGRAPH * 4);
  int* colv   = (int*)alloc((size_t)ne * 4);

  const int* srcI = ei;
  const int* dstI = ei + ne;

  dim3 blk(256);

  // weight conversions (transpose to [N=256][K] bf16)
  k_wconv<<<dim3(128 / 32, 8), blk, 0, stream>>>(enc_Win, w_enc_in, 128);
  k_wconv<<<dim3(256 / 32, 8), blk, 0, stream>>>(enc_Wh, w_enc_h0, 256);
  k_wconv<<<dim3(256 / 32, 8), blk, 0, stream>>>(enc_Wh + 256 * 256, w_enc_h1, 256);
  k_wconv<<<dim3(256 / 32, 8), blk, 0, stream>>>(enc_Wout, w_enc_out, 256);
  k_wconv<<<dim3(256 / 32, 8), blk, 0, stream>>>(proc_Win, w_proc_in, 256);
  k_wconv<<<dim3(256 / 32, 8), blk, 0, stream>>>(proc_Wh, w_proc_h0, 256);
  k_wconv<<<dim3(256 / 32, 8), blk, 0, stream>>>(proc_Wh + 256 * 256, w_proc_h1, 256);
  k_wconv<<<dim3(256 / 32, 8), blk, 0, stream>>>(proc_Wout, w_proc_out, 256);
  k_wconv<<<dim3(512 / 32, 8), blk, 0, stream>>>(edge_W, w_edge, 512);
  k_f2b<<<dim3((n * 128 / 4 + 255) / 256), blk, 0, stream>>>(x, xb, n * 128);

  // CSR by destination + per-graph bounds
  k_zero_i32<<<dim3((n + 255) / 256), blk, 0, stream>>>(cnt, n);
  k_hist<<<dim3((ne + 255) / 256), blk, 0, stream>>>(dstI, cnt, ne);
  k_scan<<<1, 1024, 0, stream>>>(cnt, rowptr, cursor, n);
  k_gbounds<<<1, 64, 0, stream>>>(batch, n, gstart, gcnt);
  k_scatter<<<dim3((ne + 255) / 256), blk, 0, stream>>>(srcI, dstI, cursor, colv, ne);

  const int nwg = ((n + 127) / 128) * 4;  // 628 (flattened, swizzled in-kernel)
  dim3 gg(nwg);

  // encoder
  k_gemm_bf16<<<gg, blk, 0, stream>>>(xb,  w_enc_in, 128, nullptr, nullptr, 0, enc_bin,      nullptr, hb0, n, 128, 1);
  k_gemm_bf16<<<gg, blk, 0, stream>>>(hb0, w_enc_h0, 256, nullptr, nullptr, 0, enc_bh,       nullptr, hb1, n, 256, 1);
  k_gemm_bf16<<<gg, blk, 0, stream>>>(hb1, w_enc_h1, 256, nullptr, nullptr, 0, enc_bh + 256, nullptr, hb0, n, 256, 1);
  k_gemm_bf16<<<gg, blk, 0, stream>>>(hb0, w_enc_out, 256, nullptr, nullptr, 0, enc_bout,    nullptr, hb1, n, 256, 0);

  // 4 message-passing rounds; h in hb1 at loop head
  for (int r = 0; r < 4; ++r) {
    k_aggregate<<<dim3((n + 3) / 4), blk, 0, stream>>>(hb1, rowptr, colv, Sb, hdb, degf, n);
    k_gemm_bf16<<<gg, blk, 0, stream>>>(hdb, w_edge, 512, Sb, w_edge + 256, 512, edge_b, degf, hb0, n, 256, 0);
    k_gemm_bf16<<<gg, blk, 0, stream>>>(hb0, w_proc_in, 256, nullptr, nullptr, 0, proc_bin,       nullptr, Sb,  n, 256, 1);
    k_gemm_bf16<<<gg, blk, 0, stream>>>(Sb,  w_proc_h0, 256, nullptr, nullptr, 0, proc_bh,        nullptr, hb0, n, 256, 1);
    k_gemm_bf16<<<gg, blk, 0, stream>>>(hb0, w_proc_h1, 256, nullptr, nullptr, 0, proc_bh + 256,  nullptr, Sb,  n, 256, 1);
    k_gemm_bf16<<<gg, blk, 0, stream>>>(Sb,  w_proc_out, 256, nullptr, nullptr, 0, proc_bout,     nullptr, hb1, n, 256, 0);
  }

  // pooling
  k_pool1<<<dim3(NGRAPH * 16), blk, 0, stream>>>(hb1, gstart, gcnt, psum, pmax);
  k_pool2<<<dim3(NGRAPH), blk, 0, stream>>>(psum, pmax, gcnt, pooled);

  // decoder: 4 parallel layer kernels
  k_dec_layer<<<dim3(4, NGRAPH), blk, 0, stream>>>(pooled, dec_Win, dec_bin, db0, 768, 256, 1);
  k_dec_layer<<<dim3(4, NGRAPH), blk, 0, stream>>>(db0, dec_Wh, dec_bh, db1, 256, 256, 1);
  k_dec_layer<<<dim3(4, NGRAPH), blk, 0, stream>>>(db1, dec_Wh + 65536, dec_bh + 256, db0, 256, 256, 1);
  k_dec_layer<<<dim3(1, NGRAPH), blk, 0, stream>>>(db0, dec_Wout, dec_bout, (float*)d_out, 256, 32, 0);
}